// Round 13
// baseline (170.371 us; speedup 1.0000x reference)
//
#include <hip/hip_runtime.h>
#include <hip/hip_bf16.h>
#include <hip/hip_cooperative_groups.h>

namespace cg = cooperative_groups;

#define L_DIM 8192
#define H_DIM 512
#define P_DIM 512
#define CHUNK 32
#define NCHUNK (L_DIM / CHUNK)   // 256

typedef __attribute__((ext_vector_type(8))) short bf16x8;
typedef __attribute__((ext_vector_type(4))) float f32x4;

__device__ inline short f2bf(float x) {
    union { float f; unsigned u; } v; v.f = x;
    unsigned r = v.u + 0x7fffu + ((v.u >> 16) & 1u);
    return (short)(r >> 16);
}
__device__ inline float bflo2f(unsigned w) {
    union { unsigned u; float f; } v; v.u = w << 16; return v.f;
}
__device__ inline float bfhi2f(unsigned w) {
    union { unsigned u; float f; } v; v.u = w & 0xffff0000u; return v.f;
}

__device__ inline void gload_lds16(const void* g, void* l) {
    __builtin_amdgcn_global_load_lds(
        (const __attribute__((address_space(1))) unsigned int*)g,
        (__attribute__((address_space(3))) unsigned int*)l, 16, 0, 0);
}

template<int N> __device__ inline void waitcnt_vm() {
    if constexpr (N == 0)       asm volatile("s_waitcnt vmcnt(0)" ::: "memory");
    else if constexpr (N == 3)  asm volatile("s_waitcnt vmcnt(3)" ::: "memory");
    else if constexpr (N == 4)  asm volatile("s_waitcnt vmcnt(4)" ::: "memory");
    else if constexpr (N == 6)  asm volatile("s_waitcnt vmcnt(6)" ::: "memory");
    else if constexpr (N == 8)  asm volatile("s_waitcnt vmcnt(8)" ::: "memory");
}

// ---------------------------------------------------------------------------
// Fused prep:
//   blocks [0,512):        discretize -> Bcat bf16, lambda_bar, lambda_powN
//   blocks [512,1536):     Ccat bf16
//   blocks [1536,3584):    u fp32 -> u_bf bf16
// ---------------------------------------------------------------------------
__global__ __launch_bounds__(256) void k_prep(
        const float* __restrict__ Lre, const float* __restrict__ Lim,
        const float* __restrict__ Bin, const float* __restrict__ log_step,
        const float* __restrict__ Cin, const float* __restrict__ u,
        short* __restrict__ Bcat, short* __restrict__ Ccat,
        short* __restrict__ u_bf,
        float* __restrict__ lambda_bar, float* __restrict__ lambda_powN) {
    const int blk = blockIdx.x;
    const int tid = threadIdx.x;
    if (blk < P_DIM) {
        int p = blk;
        float lr = Lre[p], li = Lim[p];
        float dt = expf(log_step[p]);
        float ar = lr * dt, ai = li * dt;
        float er = expf(ar);
        float lbr = er * cosf(ai);
        float lbi = er * sinf(ai);
        float nr = lbr - 1.0f, ni = lbi;
        float den = lr * lr + li * li;
        float fr = (nr * lr + ni * li) / den;
        float fi = (ni * lr - nr * li) / den;
        if (tid == 0) {
            lambda_bar[2 * p] = lbr;
            lambda_bar[2 * p + 1] = lbi;
            float eN = expf(ar * (float)CHUNK);
            lambda_powN[2 * p] = eN * cosf(ai * (float)CHUNK);
            lambda_powN[2 * p + 1] = eN * sinf(ai * (float)CHUNK);
        }
        for (int h = tid; h < H_DIM; h += 256) {
            float br = Bin[((size_t)p * H_DIM + h) * 2 + 0];
            float bi = Bin[((size_t)p * H_DIM + h) * 2 + 1];
            Bcat[(size_t)(2 * p) * H_DIM + h] = f2bf(fr * br - fi * bi);
            Bcat[(size_t)(2 * p + 1) * H_DIM + h] = f2bf(fr * bi + fi * br);
        }
    } else if (blk < P_DIM + 1024) {
        int idx = (blk - P_DIM) * 256 + tid;           // over H*P
        int h = idx >> 9, p = idx & 511;
        float cr = Cin[(size_t)idx * 2 + 0];
        float ci = Cin[(size_t)idx * 2 + 1];
        Ccat[(size_t)h * (2 * P_DIM) + 2 * p + 0] = f2bf(cr);
        Ccat[(size_t)h * (2 * P_DIM) + 2 * p + 1] = f2bf(-ci);
    } else {
        int i = (blk - P_DIM - 1024) * 256 + tid;      // over (L*H)/8
        const float4* uf = (const float4*)u;
        float4 a0 = uf[(size_t)i * 2];
        float4 a1 = uf[(size_t)i * 2 + 1];
        bf16x8 sv;
        sv[0] = f2bf(a0.x); sv[1] = f2bf(a0.y); sv[2] = f2bf(a0.z); sv[3] = f2bf(a0.w);
        sv[4] = f2bf(a1.x); sv[5] = f2bf(a1.y); sv[6] = f2bf(a1.z); sv[7] = f2bf(a1.w);
        *(bf16x8*)&u_bf[(size_t)i * 8] = sv;
    }
}

// ---------------------------------------------------------------------------
// GEMM1: 3-buffer LDS, single barrier per K-step, wait-then-publish (R12).
// Bu[L][2P](bf16 packed) = u_bf[L][H] * Bcat[2P][H]^T, + fused chunk
// summaries S. BM=128, BN=128. 1-D grid, bijective XCD swizzle.
// ---------------------------------------------------------------------------
__global__ __launch_bounds__(256) void k_gemm1(
        const short* __restrict__ A, const short* __restrict__ B,
        short* __restrict__ Cout, const float* __restrict__ Lamb,
        float* __restrict__ S) {
    constexpr int BM = 128, BN = 128;
    constexpr int MF = 4, NF = 4;
    constexpr int APL = 2, BPL = 2, LPS = 4;
    constexpr int ASZ = BM * 32 * 2;       // 8192
    constexpr int BSZ = BN * 32 * 2;       // 8192
    const int M = L_DIM, N = 2 * P_DIM, K = H_DIM;
    const int nwgn = N / BN;               // 8
    __shared__ __align__(16) char smem[3 * (ASZ + BSZ)];   // 48KB > TILE 34KB

    const int tid = threadIdx.x;
    const int lane = tid & 63;
    const int wid = tid >> 6;
    const int wr = wid >> 1, wc = wid & 1;

    const int nwg = gridDim.x;
    const int orig = blockIdx.x;
    const int id = (orig & 7) * (nwg >> 3) + (orig >> 3);
    const int bm = (id / nwgn) * BM;
    const int bn = (id % nwgn) * BN;

    f32x4 acc[MF][NF] = {};
    const int arow = wr * (BM / 2) + (lane & 15);
    const int brow = wc * (BN / 2) + (lane & 15);
    const int rslot = (((lane >> 4) ^ (lane & 3) ^ ((lane >> 2) & 3)) << 4);

    auto stage = [&](int buf, int kk) {
#pragma unroll
        for (int q = 0; q < APL; ++q) {
            int sb = q * 4096 + tid * 16;
            int row = sb >> 6, slot = (sb >> 4) & 3;
            int gs = slot ^ ((row ^ (row >> 2)) & 3);
            const char* src = (const char*)A + ((size_t)(bm + row) * K + kk) * 2 + gs * 16;
            gload_lds16(src, smem + buf * ASZ + sb);
        }
#pragma unroll
        for (int q = 0; q < BPL; ++q) {
            int sb = q * 4096 + tid * 16;
            int row = sb >> 6, slot = (sb >> 4) & 3;
            int gs = slot ^ ((row ^ (row >> 2)) & 3);
            const char* src = (const char*)B + ((size_t)(bn + row) * K + kk) * 2 + gs * 16;
            gload_lds16(src, smem + 3 * ASZ + buf * BSZ + sb);
        }
    };

    const int nt = K >> 5;                 // 16
    stage(0, 0);
    stage(1, 32);
    waitcnt_vm<LPS>();
    __builtin_amdgcn_s_barrier();
    __builtin_amdgcn_sched_barrier(0);

    for (int t = 0; t < nt; ++t) {
        const int cb = t % 3;
        const char* Ab = smem + cb * ASZ;
        const char* Bb = smem + 3 * ASZ + cb * BSZ;
        bf16x8 af[MF], bfr[NF];
#pragma unroll
        for (int m = 0; m < MF; ++m)
            af[m] = *(const bf16x8*)(Ab + (arow + m * 16) * 64 + rslot);
#pragma unroll
        for (int n = 0; n < NF; ++n)
            bfr[n] = *(const bf16x8*)(Bb + (brow + n * 16) * 64 + rslot);
        if (t + 2 < nt) stage((t + 2) % 3, (t + 2) * 32);
        __builtin_amdgcn_s_setprio(1);
#pragma unroll
        for (int m = 0; m < MF; ++m)
#pragma unroll
            for (int n = 0; n < NF; ++n)
                acc[m][n] = __builtin_amdgcn_mfma_f32_16x16x32_bf16(af[m], bfr[n], acc[m][n], 0, 0, 0);
        __builtin_amdgcn_s_setprio(0);
        if (t + 1 < nt) {
            if (t + 2 < nt) waitcnt_vm<LPS>(); else waitcnt_vm<0>();
            __builtin_amdgcn_s_barrier();
            __builtin_amdgcn_sched_barrier(0);
        }
    }

    // epilogue via LDS tile (272 B rows): bf16 out + chunk summaries
    __syncthreads();
    const int fq = lane >> 4, fr = lane & 15;
#pragma unroll
    for (int m = 0; m < MF; ++m)
#pragma unroll
        for (int n = 0; n < NF; ++n) {
            int rowL = wr * (BM / 2) + m * 16 + fq * 4;
            int colL = wc * (BN / 2) + n * 16 + fr;
#pragma unroll
            for (int j = 0; j < 4; ++j)
                *(short*)(smem + (rowL + j) * 272 + colL * 2) = f2bf(acc[m][n][j]);
        }
    __syncthreads();
    constexpr int SEGS = BN / 8;
#pragma unroll
    for (int it = 0; it < (BM * SEGS) / 256; ++it) {
        int f = it * 256 + tid;
        int row = f / SEGS, seg = f % SEGS;
        uint4 v = *(const uint4*)(smem + row * 272 + seg * 16);
        *(uint4*)(Cout + (size_t)(bm + row) * N + bn + seg * 8) = v;
    }
    {   // summaries: 64 complex channels x 4 chunks
        const int c_loc = tid >> 6;
        const int ch = tid & 63;
        const int gch = (bn >> 1) + ch;
        const float lr = Lamb[2 * gch], li = Lamb[2 * gch + 1];
        float xr = 0.f, xi = 0.f;
#pragma unroll 8
        for (int j = 0; j < CHUNK; ++j) {
            unsigned wv = *(const unsigned*)(smem + (c_loc * CHUNK + j) * 272 + ch * 4);
            float br = bflo2f(wv), bi = bfhi2f(wv);
            float nxr = lr * xr - li * xi + br;
            float nxi = lr * xi + li * xr + bi;
            xr = nxr; xi = nxi;
        }
        ((float2*)S)[(size_t)((bm >> 5) + c_loc) * P_DIM + gch] = make_float2(xr, xi);
    }
}

// ---------------------------------------------------------------------------
// Fused cooperative kernel: combine + apply + GEMM2. Grid 512 x 256.
//   Phase A (blocks 0,1): prefix over chunk summaries -> pref (identical FP
//     order to the old k_scan_combine).
//   Phase B: apply; block `id` (XCD-swizzled) scans chunks [(id/8)*4,+4) --
//     exactly the rows its Phase-C tile consumes (same-XCD L2 locality).
//   Phase C: GEMM2 y = xs_bf16 * Ccat^T + D*u. BM=128, BN=64, R12 K-loop.
// ---------------------------------------------------------------------------
__global__ __launch_bounds__(256) void k_scan_gemm2(
        const unsigned* __restrict__ Bu, unsigned* __restrict__ XsB,
        const float* __restrict__ lamb, const float* __restrict__ lamN,
        const float* __restrict__ S, float* __restrict__ pref,
        const short* __restrict__ Ccat, float* __restrict__ y,
        const float* __restrict__ Dv, const short* __restrict__ u_bf) {
    constexpr int BM = 128, BN = 64;
    constexpr int MF = 4, NF = 2;
    constexpr int APL = 2, BPL = 1, LPS = 3;
    constexpr int ASZ = BM * 32 * 2;       // 8192
    constexpr int BSZ = BN * 32 * 2;       // 4096
    __shared__ __align__(16) char smem[3 * (ASZ + BSZ)];   // 36864 >= TILE 34816

    cg::grid_group grid = cg::this_grid();
    const int tid = threadIdx.x;
    const int orig = blockIdx.x;
    const int nwg = gridDim.x;             // 512
    const int id = (orig & 7) * (nwg >> 3) + (orig >> 3);

    // ---------------- Phase A: combine (blocks 0,1) ----------------
    if (orig < 2) {
        const int ch = orig * 256 + tid;
        const float lNr = lamN[2 * ch], lNi = lamN[2 * ch + 1];
        const float2* Sp = (const float2*)S;
        float2* Pp = (float2*)pref;
        float2 curb[16], nxtb[16];
#pragma unroll
        for (int j = 0; j < 16; ++j) curb[j] = Sp[(size_t)j * P_DIM + ch];
        float xr = 0.f, xi = 0.f;
        for (int c0 = 0; c0 < NCHUNK; c0 += 16) {
            if (c0 + 16 < NCHUNK) {
#pragma unroll
                for (int j = 0; j < 16; ++j) nxtb[j] = Sp[(size_t)(c0 + 16 + j) * P_DIM + ch];
            }
#pragma unroll
            for (int j = 0; j < 16; ++j) {
                Pp[(size_t)(c0 + j) * P_DIM + ch] = make_float2(xr, xi);
                float nxr = lNr * xr - lNi * xi + curb[j].x;
                float nxi = lNr * xi + lNi * xr + curb[j].y;
                xr = nxr; xi = nxi;
            }
#pragma unroll
            for (int j = 0; j < 16; ++j) curb[j] = nxtb[j];
        }
    }
    grid.sync();

    // ---------------- Phase B: apply (XCD-aligned mapping) ----------------
    {
        const int c = (id >> 3) * 4 + ((id & 7) >> 1);   // chunk
        const int p = (id & 1) * 256 + tid;              // channel
        const float lr = lamb[2 * p], li = lamb[2 * p + 1];
        float2 x0 = ((const float2*)pref)[(size_t)c * P_DIM + p];
        float xr = x0.x, xi = x0.y;
        const unsigned* bu = Bu + (size_t)c * CHUNK * P_DIM + p;
#pragma unroll 4
        for (int j = 0; j < CHUNK; ++j) {
            unsigned w = bu[(size_t)j * P_DIM];
            float br = bflo2f(w), bi = bfhi2f(w);
            float nxr = lr * xr - li * xi + br;
            float nxi = lr * xi + li * xr + bi;
            xr = nxr; xi = nxi;
            unsigned pk = (unsigned)(unsigned short)f2bf(xr)
                        | ((unsigned)(unsigned short)f2bf(xi) << 16);
            XsB[((size_t)c * CHUNK + j) * P_DIM + p] = pk;
        }
    }
    grid.sync();

    // ---------------- Phase C: GEMM2 ----------------
    const short* A = (const short*)XsB;
    const int M = L_DIM, N = H_DIM, K = 2 * P_DIM;
    const int nwgn = N / BN;               // 8
    const int lane = tid & 63;
    const int wid = tid >> 6;
    const int wr = wid >> 1, wc = wid & 1;
    const int bm = (id / nwgn) * BM;
    const int bn = (id % nwgn) * BN;

    f32x4 acc[MF][NF] = {};
    const int arow = wr * (BM / 2) + (lane & 15);
    const int brow = wc * (BN / 2) + (lane & 15);
    const int rslot = (((lane >> 4) ^ (lane & 3) ^ ((lane >> 2) & 3)) << 4);

    auto stage = [&](int buf, int kk) {
#pragma unroll
        for (int q = 0; q < APL; ++q) {
            int sb = q * 4096 + tid * 16;
            int row = sb >> 6, slot = (sb >> 4) & 3;
            int gs = slot ^ ((row ^ (row >> 2)) & 3);
            const char* src = (const char*)A + ((size_t)(bm + row) * K + kk) * 2 + gs * 16;
            gload_lds16(src, smem + buf * ASZ + sb);
        }
#pragma unroll
        for (int q = 0; q < BPL; ++q) {
            int sb = q * 4096 + tid * 16;
            int row = sb >> 6, slot = (sb >> 4) & 3;
            int gs = slot ^ ((row ^ (row >> 2)) & 3);
            const char* src = (const char*)Ccat + ((size_t)(bn + row) * K + kk) * 2 + gs * 16;
            gload_lds16(src, smem + 3 * ASZ + buf * BSZ + sb);
        }
    };

    const int nt = K >> 5;                 // 32
    stage(0, 0);
    stage(1, 32);
    waitcnt_vm<LPS>();
    __builtin_amdgcn_s_barrier();
    __builtin_amdgcn_sched_barrier(0);

    for (int t = 0; t < nt; ++t) {
        const int cb = t % 3;
        const char* Ab = smem + cb * ASZ;
        const char* Bb = smem + 3 * ASZ + cb * BSZ;
        bf16x8 af[MF], bfr[NF];
#pragma unroll
        for (int m = 0; m < MF; ++m)
            af[m] = *(const bf16x8*)(Ab + (arow + m * 16) * 64 + rslot);
#pragma unroll
        for (int n = 0; n < NF; ++n)
            bfr[n] = *(const bf16x8*)(Bb + (brow + n * 16) * 64 + rslot);
        if (t + 2 < nt) stage((t + 2) % 3, (t + 2) * 32);
        __builtin_amdgcn_s_setprio(1);
#pragma unroll
        for (int m = 0; m < MF; ++m)
#pragma unroll
            for (int n = 0; n < NF; ++n)
                acc[m][n] = __builtin_amdgcn_mfma_f32_16x16x32_bf16(af[m], bfr[n], acc[m][n], 0, 0, 0);
        __builtin_amdgcn_s_setprio(0);
        if (t + 1 < nt) {
            if (t + 2 < nt) waitcnt_vm<LPS>(); else waitcnt_vm<0>();
            __builtin_amdgcn_s_barrier();
            __builtin_amdgcn_sched_barrier(0);
        }
    }

    // epilogue via LDS tile (272 B rows), fp32 out + D*u
    __syncthreads();
    const int fq = lane >> 4, fr = lane & 15;
#pragma unroll
    for (int m = 0; m < MF; ++m)
#pragma unroll
        for (int n = 0; n < NF; ++n) {
            int rowL = wr * (BM / 2) + m * 16 + fq * 4;
            int colL = wc * (BN / 2) + n * 16 + fr;
#pragma unroll
            for (int j = 0; j < 4; ++j)
                *(float*)(smem + (rowL + j) * 272 + colL * 4) = acc[m][n][j];
        }
    __syncthreads();
    constexpr int SEGS = BN / 4;
#pragma unroll
    for (int it = 0; it < (BM * SEGS) / 256; ++it) {
        int f = it * 256 + tid;
        int row = f / SEGS, seg = f % SEGS;
        float4 v = *(const float4*)(smem + row * 272 + seg * 16);
        int gr = bm + row, gc = bn + seg * 4;
        const short* up = u_bf + (size_t)gr * N + gc;
        short4 us = *(const short4*)up;
        float4 dv = *(const float4*)(Dv + gc);
        v.x += dv.x * bflo2f((unsigned)(unsigned short)us.x);
        v.y += dv.y * bflo2f((unsigned)(unsigned short)us.y);
        v.z += dv.z * bflo2f((unsigned)(unsigned short)us.z);
        v.w += dv.w * bflo2f((unsigned)(unsigned short)us.w);
        *(float4*)(y + (size_t)gr * N + gc) = v;
    }
}

// ---------------------------------------------------------------------------
extern "C" void kernel_launch(void* const* d_in, const int* in_sizes, int n_in,
                              void* d_out, int out_size, void* d_ws, size_t ws_size,
                              hipStream_t stream) {
    const float* u        = (const float*)d_in[0];
    const float* Lre      = (const float*)d_in[1];
    const float* Lim      = (const float*)d_in[2];
    const float* Bin      = (const float*)d_in[3];
    const float* Cin      = (const float*)d_in[4];
    const float* Dv       = (const float*)d_in[5];
    const float* log_step = (const float*)d_in[6];
    float* y = (float*)d_out;

    char* w = (char*)d_ws;
    size_t off = 0;
    short* Bcat = (short*)(w + off); off += (size_t)2 * P_DIM * H_DIM * 2;   // 1 MB
    short* Ccat = (short*)(w + off); off += (size_t)2 * P_DIM * H_DIM * 2;   // 1 MB
    float* lamb = (float*)(w + off); off += 2 * P_DIM * 4;
    float* lamN = (float*)(w + off); off += 2 * P_DIM * 4;
    float* S    = (float*)(w + off); off += (size_t)NCHUNK * 2 * P_DIM * 4;  // 1 MB
    float* pref = (float*)(w + off); off += (size_t)NCHUNK * 2 * P_DIM * 4;  // 1 MB
    unsigned* Bu  = (unsigned*)(w + off); off += (size_t)L_DIM * P_DIM * 4;  // 16 MB (packed bf16)
    unsigned* XsB = (unsigned*)(w + off); off += (size_t)L_DIM * P_DIM * 4;  // 16 MB (packed bf16)
    short* u_bf   = (short*)(w + off);   off += (size_t)L_DIM * H_DIM * 2;   // 8 MB

    // prep: discretize + Ccat + u->bf16
    k_prep<<<P_DIM + 1024 + 2048, 256, 0, stream>>>(
        Lre, Lim, Bin, log_step, Cin, u, Bcat, Ccat, u_bf, lamb, lamN);
    // GEMM1 (+fused chunk summaries)
    k_gemm1<<<(L_DIM / 128) * ((2 * P_DIM) / 128), 256, 0, stream>>>(
        u_bf, Bcat, (short*)Bu, lamb, S);
    // Fused combine + apply + GEMM2 (cooperative, grid 512 co-resident)
    {
        const unsigned* BuC = Bu;
        unsigned* XsBp = XsB;
        const float* lambC = lamb;
        const float* lamNC = lamN;
        const float* SC = S;
        float* prefP = pref;
        const short* CcatC = Ccat;
        float* yP = y;
        const float* DvC = Dv;
        const short* u_bfC = u_bf;
        void* kargs[10] = {&BuC, &XsBp, &lambC, &lamNC, &SC, &prefP,
                           &CcatC, &yP, &DvC, &u_bfC};
        hipLaunchCooperativeKernel((void*)k_scan_gemm2, dim3(512), dim3(256),
                                   kargs, 0, stream);
    }
}

// Round 14
// 67.566 us; speedup vs baseline: 2.5215x; 2.5215x over previous
//
#include <hip/hip_runtime.h>
#include <hip/hip_bf16.h>

#define L_DIM 8192
#define H_DIM 512
#define P_DIM 512
#define CHUNK 32
#define NCHUNK (L_DIM / CHUNK)   // 256

typedef __attribute__((ext_vector_type(8))) short bf16x8;
typedef __attribute__((ext_vector_type(4))) float f32x4;

__device__ inline short f2bf(float x) {
    union { float f; unsigned u; } v; v.f = x;
    unsigned r = v.u + 0x7fffu + ((v.u >> 16) & 1u);
    return (short)(r >> 16);
}
__device__ inline float bflo2f(unsigned w) {
    union { unsigned u; float f; } v; v.u = w << 16; return v.f;
}
__device__ inline float bfhi2f(unsigned w) {
    union { unsigned u; float f; } v; v.u = w & 0xffff0000u; return v.f;
}

__device__ inline void gload_lds16(const void* g, void* l) {
    __builtin_amdgcn_global_load_lds(
        (const __attribute__((address_space(1))) unsigned int*)g,
        (__attribute__((address_space(3))) unsigned int*)l, 16, 0, 0);
}

template<int N> __device__ inline void waitcnt_vm() {
    if constexpr (N == 0)      asm volatile("s_waitcnt vmcnt(0)" ::: "memory");
    else if constexpr (N == 3) asm volatile("s_waitcnt vmcnt(3)" ::: "memory");
    else if constexpr (N == 4) asm volatile("s_waitcnt vmcnt(4)" ::: "memory");
    else if constexpr (N == 6) asm volatile("s_waitcnt vmcnt(6)" ::: "memory");
    else if constexpr (N == 8) asm volatile("s_waitcnt vmcnt(8)" ::: "memory");
}

// ---------------------------------------------------------------------------
// Fused prep:
//   blocks [0,512):        discretize -> Bcat bf16, lambda_bar, lambda_powN
//   blocks [512,1536):     Ccat bf16
//   blocks [1536,3584):    u fp32 -> u_bf bf16
// ---------------------------------------------------------------------------
__global__ __launch_bounds__(256) void k_prep(
        const float* __restrict__ Lre, const float* __restrict__ Lim,
        const float* __restrict__ Bin, const float* __restrict__ log_step,
        const float* __restrict__ Cin, const float* __restrict__ u,
        short* __restrict__ Bcat, short* __restrict__ Ccat,
        short* __restrict__ u_bf,
        float* __restrict__ lambda_bar, float* __restrict__ lambda_powN) {
    const int blk = blockIdx.x;
    const int tid = threadIdx.x;
    if (blk < P_DIM) {
        int p = blk;
        float lr = Lre[p], li = Lim[p];
        float dt = expf(log_step[p]);
        float ar = lr * dt, ai = li * dt;
        float er = expf(ar);
        float lbr = er * cosf(ai);
        float lbi = er * sinf(ai);
        float nr = lbr - 1.0f, ni = lbi;
        float den = lr * lr + li * li;
        float fr = (nr * lr + ni * li) / den;
        float fi = (ni * lr - nr * li) / den;
        if (tid == 0) {
            lambda_bar[2 * p] = lbr;
            lambda_bar[2 * p + 1] = lbi;
            float eN = expf(ar * (float)CHUNK);
            lambda_powN[2 * p] = eN * cosf(ai * (float)CHUNK);
            lambda_powN[2 * p + 1] = eN * sinf(ai * (float)CHUNK);
        }
        for (int h = tid; h < H_DIM; h += 256) {
            float br = Bin[((size_t)p * H_DIM + h) * 2 + 0];
            float bi = Bin[((size_t)p * H_DIM + h) * 2 + 1];
            Bcat[(size_t)(2 * p) * H_DIM + h] = f2bf(fr * br - fi * bi);
            Bcat[(size_t)(2 * p + 1) * H_DIM + h] = f2bf(fr * bi + fi * br);
        }
    } else if (blk < P_DIM + 1024) {
        int idx = (blk - P_DIM) * 256 + tid;           // over H*P
        int h = idx >> 9, p = idx & 511;
        float cr = Cin[(size_t)idx * 2 + 0];
        float ci = Cin[(size_t)idx * 2 + 1];
        Ccat[(size_t)h * (2 * P_DIM) + 2 * p + 0] = f2bf(cr);
        Ccat[(size_t)h * (2 * P_DIM) + 2 * p + 1] = f2bf(-ci);
    } else {
        int i = (blk - P_DIM - 1024) * 256 + tid;      // over (L*H)/8
        const float4* uf = (const float4*)u;
        float4 a0 = uf[(size_t)i * 2];
        float4 a1 = uf[(size_t)i * 2 + 1];
        bf16x8 sv;
        sv[0] = f2bf(a0.x); sv[1] = f2bf(a0.y); sv[2] = f2bf(a0.z); sv[3] = f2bf(a0.w);
        sv[4] = f2bf(a1.x); sv[5] = f2bf(a1.y); sv[6] = f2bf(a1.z); sv[7] = f2bf(a1.w);
        *(bf16x8*)&u_bf[(size_t)i * 8] = sv;
    }
}

// ---------------------------------------------------------------------------
// MFMA GEMM, counted-vmcnt 3-buffer pipeline, swizzled LDS, LDS epilogue.
//   out[M][N] = A[M][K] * B[N][K]^T, A/B bf16.
//   BM=128, BK=32, BN template (128 or 64). 4 waves (2x2), 16x16x32 MFMA.
//   Staging swizzle: slot ^= (row ^ row>>2)&3 on global src AND ds_read addr.
//   Pipeline: 2-deep prefetch, s_waitcnt vmcnt(2*LPS) + raw s_barrier.
//   Epilogue: acc -> LDS tile (row stride 272 B) -> fully coalesced 16B
//   global stores. OBF16: bf16 out (+SUMM: fused per-chunk scan summaries).
//   EPI: out += Dv[n]*bf2f(Ubf[m][n]) with coalesced Ubf/Dv loads.
// 1-D grid, bijective XCD swizzle (nwg % 8 == 0).
// ---------------------------------------------------------------------------
template<int BN, bool OBF16, bool EPI, bool SUMM>
__global__ __launch_bounds__(256) void k_gemm(
        const short* __restrict__ A, const short* __restrict__ B,
        void* __restrict__ Cout, int M, int N, int K, int nwgn,
        const float* __restrict__ Dv, const short* __restrict__ Ubf,
        const float* __restrict__ Lamb, float* __restrict__ S) {
    constexpr int NF = BN / 32;            // B frags per wave
    constexpr int LPS = 2 + BN / 64;       // gload_lds insts per thread per stage
    constexpr int ASZ = 128 * 32 * 2;      // bytes per A buffer
    constexpr int BSZ = BN * 32 * 2;       // bytes per B buffer
    constexpr int STG = 3 * (ASZ + BSZ);
    constexpr int TILE = 128 * 272;        // epilogue tile (both dtypes)
    constexpr int SMEM_SZ = STG > TILE ? STG : TILE;
    __shared__ __align__(16) char smem[SMEM_SZ];

    const int tid = threadIdx.x;
    const int lane = tid & 63;
    const int wid = tid >> 6;
    const int wr = wid >> 1, wc = wid & 1;

    const int nwg = gridDim.x;
    const int orig = blockIdx.x;
    const int id = (orig & 7) * (nwg >> 3) + (orig >> 3);
    const int bm = (id / nwgn) * 128;
    const int bn = (id % nwgn) * BN;

    f32x4 acc[4][NF] = {};
    const int arow = wr * 64 + (lane & 15);
    const int brow = wc * (BN / 2) + (lane & 15);
    const int rslot = (((lane >> 4) ^ (lane & 3) ^ ((lane >> 2) & 3)) << 4);

    auto stage = [&](int buf, int kk) {
#pragma unroll
        for (int q = 0; q < 2; ++q) {              // A: 8192B / (256thr*16B)
            int sb = q * 4096 + tid * 16;
            int row = sb >> 6, slot = (sb >> 4) & 3;
            int gs = slot ^ ((row ^ (row >> 2)) & 3);
            const char* src = (const char*)A + ((size_t)(bm + row) * K + kk) * 2 + gs * 16;
            gload_lds16(src, smem + buf * ASZ + sb);
        }
#pragma unroll
        for (int q = 0; q < BN / 64; ++q) {        // B: BN*64B
            int sb = q * 4096 + tid * 16;
            int row = sb >> 6, slot = (sb >> 4) & 3;
            int gs = slot ^ ((row ^ (row >> 2)) & 3);
            const char* src = (const char*)B + ((size_t)(bn + row) * K + kk) * 2 + gs * 16;
            gload_lds16(src, smem + 3 * ASZ + buf * BSZ + sb);
        }
    };

    const int nt = K >> 5;
    stage(0, 0);
    stage(1, 32);

    int cur = 0, stg = 2;
    for (int t = 0; t < nt; ++t) {
        if (t + 2 < nt) {
            stage(stg, (t + 2) * 32);
            waitcnt_vm<2 * LPS>();
        } else if (t + 1 < nt) {
            waitcnt_vm<LPS>();
        } else {
            waitcnt_vm<0>();
        }
        __builtin_amdgcn_s_barrier();
        __builtin_amdgcn_sched_barrier(0);

        const char* Ab = smem + cur * ASZ;
        const char* Bb = smem + 3 * ASZ + cur * BSZ;
        bf16x8 af[4], bfr[NF];
#pragma unroll
        for (int m = 0; m < 4; ++m)
            af[m] = *(const bf16x8*)(Ab + (arow + m * 16) * 64 + rslot);
#pragma unroll
        for (int n = 0; n < NF; ++n)
            bfr[n] = *(const bf16x8*)(Bb + (brow + n * 16) * 64 + rslot);
        __builtin_amdgcn_s_setprio(1);
#pragma unroll
        for (int m = 0; m < 4; ++m)
#pragma unroll
            for (int n = 0; n < NF; ++n)
                acc[m][n] = __builtin_amdgcn_mfma_f32_16x16x32_bf16(af[m], bfr[n], acc[m][n], 0, 0, 0);
        __builtin_amdgcn_s_setprio(0);

        if (t + 1 < nt) __builtin_amdgcn_s_barrier();
        cur = (cur == 2) ? 0 : cur + 1;
        stg = (stg == 2) ? 0 : stg + 1;
    }

    // ------------------- epilogue via LDS tile (272 B rows) -------------------
    __syncthreads();          // all waves done with staging buffers
    const int fq = lane >> 4, fr = lane & 15;

    if (OBF16) {
#pragma unroll
        for (int m = 0; m < 4; ++m)
#pragma unroll
            for (int n = 0; n < NF; ++n) {
                int rowL = wr * 64 + m * 16 + fq * 4;
                int colL = wc * (BN / 2) + n * 16 + fr;
#pragma unroll
                for (int j = 0; j < 4; ++j)
                    *(short*)(smem + (rowL + j) * 272 + colL * 2) = f2bf(acc[m][n][j]);
            }
        __syncthreads();
        constexpr int SEGS = BN / 8;              // 16B segments per row
#pragma unroll
        for (int it = 0; it < (128 * SEGS) / 256; ++it) {
            int f = it * 256 + tid;
            int row = f / SEGS, seg = f % SEGS;
            uint4 v = *(const uint4*)(smem + row * 272 + seg * 16);
            *(uint4*)((short*)Cout + (size_t)(bm + row) * N + bn + seg * 8) = v;
        }
        if (SUMM) {
            // 256 threads -> 4 chunks x 64 complex channels
            const int c_loc = tid >> 6;
            const int ch = tid & 63;
            const int gch = (bn >> 1) + ch;
            const float lr = Lamb[2 * gch], li = Lamb[2 * gch + 1];
            float xr = 0.f, xi = 0.f;
#pragma unroll 8
            for (int j = 0; j < 32; ++j) {
                unsigned wv = *(const unsigned*)(smem + (c_loc * 32 + j) * 272 + ch * 4);
                float br = bflo2f(wv), bi = bfhi2f(wv);
                float nxr = lr * xr - li * xi + br;
                float nxi = lr * xi + li * xr + bi;
                xr = nxr; xi = nxi;
            }
            ((float2*)S)[(size_t)((bm >> 5) + c_loc) * P_DIM + gch] = make_float2(xr, xi);
        }
    } else {
#pragma unroll
        for (int m = 0; m < 4; ++m)
#pragma unroll
            for (int n = 0; n < NF; ++n) {
                int rowL = wr * 64 + m * 16 + fq * 4;
                int colL = wc * (BN / 2) + n * 16 + fr;
#pragma unroll
                for (int j = 0; j < 4; ++j)
                    *(float*)(smem + (rowL + j) * 272 + colL * 4) = acc[m][n][j];
            }
        __syncthreads();
        constexpr int SEGS = BN / 4;              // 16B segments per row (f32)
#pragma unroll
        for (int it = 0; it < (128 * SEGS) / 256; ++it) {
            int f = it * 256 + tid;
            int row = f / SEGS, seg = f % SEGS;
            float4 v = *(const float4*)(smem + row * 272 + seg * 16);
            int gr = bm + row, gc = bn + seg * 4;
            if (EPI) {
                const short* up = Ubf + (size_t)gr * N + gc;
                short4 us = *(const short4*)up;
                float4 dv = *(const float4*)(Dv + gc);
                v.x += dv.x * bflo2f((unsigned)(unsigned short)us.x);
                v.y += dv.y * bflo2f((unsigned)(unsigned short)us.y);
                v.z += dv.z * bflo2f((unsigned)(unsigned short)us.z);
                v.w += dv.w * bflo2f((unsigned)(unsigned short)us.w);
            }
            *(float4*)((float*)Cout + (size_t)gr * N + gc) = v;
        }
    }
}

// ---------------------------------------------------------------------------
// Combine: prefix over chunk summaries. 8 blocks x 64 threads (1 ch each),
// sequential in c (same FP order as before), register double-buffered
// 16-deep batches so L2 latency hides under the 16-step compute.
// ---------------------------------------------------------------------------
__global__ __launch_bounds__(64) void k_scan_combine(const float* __restrict__ S,
                                                     const float* __restrict__ lambda_powN,
                                                     float* __restrict__ pref) {
    const int ch = blockIdx.x * 64 + threadIdx.x;
    const float lNr = lambda_powN[2 * ch], lNi = lambda_powN[2 * ch + 1];
    const float2* Sp = (const float2*)S;
    float2* Pp = (float2*)pref;
    float2 curb[16], nxtb[16];
#pragma unroll
    for (int j = 0; j < 16; ++j) curb[j] = Sp[(size_t)j * P_DIM + ch];
    float xr = 0.f, xi = 0.f;
    for (int c0 = 0; c0 < NCHUNK; c0 += 16) {
        if (c0 + 16 < NCHUNK) {
#pragma unroll
            for (int j = 0; j < 16; ++j) nxtb[j] = Sp[(size_t)(c0 + 16 + j) * P_DIM + ch];
        }
#pragma unroll
        for (int j = 0; j < 16; ++j) {
            Pp[(size_t)(c0 + j) * P_DIM + ch] = make_float2(xr, xi);
            float nxr = lNr * xr - lNi * xi + curb[j].x;
            float nxi = lNr * xi + lNi * xr + curb[j].y;
            xr = nxr; xi = nxi;
        }
#pragma unroll
        for (int j = 0; j < 16; ++j) curb[j] = nxtb[j];
    }
}

// ---------------------------------------------------------------------------
// Apply: fully parallel, prefix given. Bu packed bf16 -> XsB packed bf16.
// ---------------------------------------------------------------------------
__global__ __launch_bounds__(256) void k_scan_apply(const unsigned* __restrict__ Bu,
                                                    unsigned* __restrict__ XsB,
                                                    const float* __restrict__ lambda_bar,
                                                    const float* __restrict__ pref) {
    int gid = blockIdx.x * blockDim.x + threadIdx.x;   // NCHUNK*P threads
    int c = gid >> 9, p = gid & 511;
    const float lr = lambda_bar[2 * p], li = lambda_bar[2 * p + 1];
    float2 x0 = ((const float2*)pref)[(size_t)c * P_DIM + p];
    float xr = x0.x, xi = x0.y;
    const unsigned* bu = Bu + (size_t)c * CHUNK * P_DIM + p;
#pragma unroll 4
    for (int j = 0; j < CHUNK; ++j) {
        unsigned w = bu[(size_t)j * P_DIM];
        float br = bflo2f(w), bi = bfhi2f(w);
        float nxr = lr * xr - li * xi + br;
        float nxi = lr * xi + li * xr + bi;
        xr = nxr; xi = nxi;
        unsigned pk = (unsigned)(unsigned short)f2bf(xr)
                    | ((unsigned)(unsigned short)f2bf(xi) << 16);
        XsB[((size_t)c * CHUNK + j) * P_DIM + p] = pk;
    }
}

// ---------------------------------------------------------------------------
extern "C" void kernel_launch(void* const* d_in, const int* in_sizes, int n_in,
                              void* d_out, int out_size, void* d_ws, size_t ws_size,
                              hipStream_t stream) {
    const float* u        = (const float*)d_in[0];
    const float* Lre      = (const float*)d_in[1];
    const float* Lim      = (const float*)d_in[2];
    const float* Bin      = (const float*)d_in[3];
    const float* Cin      = (const float*)d_in[4];
    const float* Dv       = (const float*)d_in[5];
    const float* log_step = (const float*)d_in[6];
    float* y = (float*)d_out;

    char* w = (char*)d_ws;
    size_t off = 0;
    short* Bcat = (short*)(w + off); off += (size_t)2 * P_DIM * H_DIM * 2;   // 1 MB
    short* Ccat = (short*)(w + off); off += (size_t)2 * P_DIM * H_DIM * 2;   // 1 MB
    float* lamb = (float*)(w + off); off += 2 * P_DIM * 4;
    float* lamN = (float*)(w + off); off += 2 * P_DIM * 4;
    float* S    = (float*)(w + off); off += (size_t)NCHUNK * 2 * P_DIM * 4;  // 1 MB
    float* pref = (float*)(w + off); off += (size_t)NCHUNK * 2 * P_DIM * 4;  // 1 MB
    unsigned* Bu  = (unsigned*)(w + off); off += (size_t)L_DIM * P_DIM * 4;  // 16 MB (packed bf16)
    unsigned* XsB = (unsigned*)(w + off); off += (size_t)L_DIM * P_DIM * 4;  // 16 MB (packed bf16)
    short* u_bf   = (short*)(w + off);   off += (size_t)L_DIM * H_DIM * 2;   // 8 MB

    // prep: discretize + Ccat + u->bf16
    k_prep<<<P_DIM + 1024 + 2048, 256, 0, stream>>>(
        Lre, Lim, Bin, log_step, Cin, u, Bcat, Ccat, u_bf, lamb, lamN);
    // GEMM1 (+fused chunk summaries): Bu[L][2P](bf16 packed) = u_bf * Bcat^T
    k_gemm<128, true, false, true><<<(L_DIM / 128) * ((2 * P_DIM) / 128), 256, 0, stream>>>(
        u_bf, Bcat, (void*)Bu, L_DIM, 2 * P_DIM, H_DIM, (2 * P_DIM) / 128,
        nullptr, nullptr, lamb, S);
    // Combine + apply
    k_scan_combine<<<8, 64, 0, stream>>>(S, lamN, pref);
    k_scan_apply<<<(NCHUNK * P_DIM) / 256, 256, 0, stream>>>(Bu, XsB, lamb, pref);
    // GEMM2: y[L][H] = xs_bf16[L][2P] * Ccat[H][2P]^T + D*u   (BN=64 -> 512 wgs)
    k_gemm<64, false, true, false><<<(L_DIM / 128) * (H_DIM / 64), 256, 0, stream>>>(
        (const short*)XsB, Ccat, (void*)y, L_DIM, H_DIM, 2 * P_DIM, H_DIM / 64,
        Dv, u_bf, nullptr, nullptr);
}